// Round 6
// baseline (182.310 us; speedup 1.0000x reference)
//
#include <hip/hip_runtime.h>
#include <hip/hip_bf16.h>
#include <math.h>

#define BB 4
#define NN 1024
#define DIMM 256
#define HEADS 8
#define DH 64
#define INNERD 512
#define NT 16
#define MDPLANE 4194304   // B*N*N

typedef __bf16 bf16x8 __attribute__((ext_vector_type(8)));
typedef float f32x4 __attribute__((ext_vector_type(4)));

// Trans-free GELU: clamp to [-3,3] + degree-9 odd poly for erf(x/sqrt2).
__device__ __forceinline__ float gelu_poly(float x) {
    float xc = fminf(fmaxf(x, -3.0f), 3.0f);
    float u = xc * xc;
    float f = fmaf(u, fmaf(u, fmaf(u, fmaf(u, 4.4413e-5f, -1.33195e-3f),
                                   1.70980e-2f), -1.299964e-1f), 7.9734583e-1f);
    float E = xc * f;
    float hx = 0.5f * xc;
    float g = fmaf(hx, E, hx);
    return g + fmaxf(x - 3.0f, 0.0f);
}
__device__ __forceinline__ float leaky_f(float x) {
    return fmaxf(x, 0.01f * x);
}

// ---------------- K1: LayerNorm (bf16 out) ----------------
__global__ __launch_bounds__(256) void ln_kernel(const float* __restrict__ feat,
                                                 const float* __restrict__ gamma,
                                                 const float* __restrict__ beta,
                                                 __hip_bfloat16* __restrict__ xb) {
    int row = blockIdx.x;
    int t = threadIdx.x;
    float v = feat[row * DIMM + t];
    float s = v, ss = v * v;
    #pragma unroll
    for (int off = 1; off < 64; off <<= 1) {
        s += __shfl_xor(s, off);
        ss += __shfl_xor(ss, off);
    }
    __shared__ float red[2][4];
    int w = t >> 6, lane = t & 63;
    if (lane == 0) { red[0][w] = s; red[1][w] = ss; }
    __syncthreads();
    s = red[0][0] + red[0][1] + red[0][2] + red[0][3];
    ss = red[1][0] + red[1][1] + red[1][2] + red[1][3];
    float mu = s * (1.0f / DIMM);
    float var = ss * (1.0f / DIMM) - mu * mu;
    float rs = rsqrtf(var + 1e-5f);
    xb[row * DIMM + t] = __float2bfloat16((v - mu) * rs * gamma[t] + beta[t]);
}

// ---------------- K2a: generic transpose-convert W[R][C] f32 -> Wt[C][R] bf16 ----------------
// grid (C/64, R/64)
__global__ __launch_bounds__(256) void wtg_kernel(const float* __restrict__ W,
                                                  __hip_bfloat16* __restrict__ Wt,
                                                  int C, int R) {
    __shared__ float tile[64][65];
    int n0 = blockIdx.x * 64, k0 = blockIdx.y * 64;
    int tid = threadIdx.x;
    int cc = tid & 63, rr = tid >> 6;
    #pragma unroll
    for (int p = 0; p < 16; ++p) {
        int k = rr + p * 4;
        tile[k][cc] = W[(k0 + k) * C + n0 + cc];
    }
    __syncthreads();
    #pragma unroll
    for (int p = 0; p < 16; ++p) {
        int n = rr + p * 4;
        Wt[(n0 + n) * R + k0 + cc] = __float2bfloat16(tile[cc][n]);
    }
}

// ---------------- fused mid: dmlp blocks (0..4095) || qkv GEMM blocks (4096..5631) ----------------
__device__ __forceinline__ void qkv_body(int bx,
                                         const __hip_bfloat16* __restrict__ xb,
                                         const __hip_bfloat16* __restrict__ Wt,
                                         __hip_bfloat16* __restrict__ qb,
                                         __hip_bfloat16* __restrict__ kb,
                                         __hip_bfloat16* __restrict__ vtb) {
    int mt = bx & 63, nt = bx >> 6;
    int tid = threadIdx.x, w = tid >> 6, lane = tid & 63;
    int g = lane >> 4, c = lane & 15;

    const __hip_bfloat16* ap = xb + (mt * 64 + w * 16 + c) * 256 + g * 8;
    bf16x8 a[8];
    #pragma unroll
    for (int ks = 0; ks < 8; ++ks) a[ks] = *reinterpret_cast<const bf16x8*>(ap + ks * 32);

    f32x4 acc[4];
    #pragma unroll
    for (int jf = 0; jf < 4; ++jf) { acc[jf][0] = 0.f; acc[jf][1] = 0.f; acc[jf][2] = 0.f; acc[jf][3] = 0.f; }

    const __hip_bfloat16* bp = Wt + (nt * 64 + c) * 256 + g * 8;
    #pragma unroll
    for (int jf = 0; jf < 4; ++jf) {
        const __hip_bfloat16* bpj = bp + jf * 16 * 256;
        #pragma unroll
        for (int ks = 0; ks < 8; ++ks) {
            bf16x8 bfrag = *reinterpret_cast<const bf16x8*>(bpj + ks * 32);
            acc[jf] = __builtin_amdgcn_mfma_f32_16x16x32_bf16(a[ks], bfrag, acc[jf], 0, 0, 0);
        }
    }

    int col0 = nt * 64;
    int part = col0 >> 9;            // 0=q,1=k,2=v
    int h = (col0 >> 6) & 7;
    #pragma unroll
    for (int jf = 0; jf < 4; ++jf) {
        int d = jf * 16 + c;
        #pragma unroll
        for (int r = 0; r < 4; ++r) {
            int m = mt * 64 + w * 16 + g * 4 + r;
            int b = m >> 10, nn = m & 1023;
            if (part == 0)
                qb[(((b * HEADS + h) * NN) + nn) * DH + d] = __float2bfloat16(acc[jf][r] * 0.125f);
            else if (part == 1)
                kb[(((b * HEADS + h) * NN) + nn) * DH + d] = __float2bfloat16(acc[jf][r]);
            else
                vtb[((long)(b * HEADS + h) * DH + d) * NN + nn] = __float2bfloat16(acc[jf][r]);
        }
    }
}

__device__ __forceinline__ void dmlp_body(int bi,
                                          const float* __restrict__ xyz,
                                          const float* __restrict__ Wp1,
                                          const float* __restrict__ Wp2,
                                          const float* __restrict__ Wn1,
                                          const float* __restrict__ Wn2,
                                          const float* __restrict__ Wc,
                                          const float* __restrict__ bc,
                                          float* __restrict__ md) {
    int tid = threadIdx.x;
    int b = bi >> 10;
    const float* xj = xyz + (long)b * NN * 3;
    float xi0 = xyz[bi * 3 + 0], xi1 = xyz[bi * 3 + 1], xi2 = xyz[bi * 3 + 2];

    float d0[4], d1[4], d2[4];
    #pragma unroll
    for (int p = 0; p < 4; ++p) {
        int j = tid + p * 256;
        d0[p] = xj[j * 3 + 0] - xi0;
        d1[p] = xj[j * 3 + 1] - xi1;
        d2[p] = xj[j * 3 + 2] - xi2;
    }

    float pp0[4], pp1[4], pp2[4], nv0[4], nv1[4], nv2[4];
    {   // pos branch
        float r0[4], r1[4], r2[4];
        float a0[4] = {}, a1[4] = {}, a2[4] = {};
        #pragma unroll
        for (int p = 0; p < 4; ++p) {
            r0[p] = fmaxf(d0[p], 0.f); r1[p] = fmaxf(d1[p], 0.f); r2[p] = fmaxf(d2[p], 0.f);
        }
        #pragma unroll
        for (int m = 0; m < 16; ++m) {
            float w0 = Wp1[m], w1 = Wp1[16 + m], w2 = Wp1[32 + m];
            float u0 = Wp2[3 * m], u1 = Wp2[3 * m + 1], u2 = Wp2[3 * m + 2];
            #pragma unroll
            for (int p = 0; p < 4; ++p) {
                float t = fmaf(r0[p], w0, fmaf(r1[p], w1, r2[p] * w2));
                t = gelu_poly(t);
                a0[p] = fmaf(t, u0, a0[p]);
                a1[p] = fmaf(t, u1, a1[p]);
                a2[p] = fmaf(t, u2, a2[p]);
            }
        }
        #pragma unroll
        for (int p = 0; p < 4; ++p) {
            pp0[p] = leaky_f(a0[p]); pp1[p] = leaky_f(a1[p]); pp2[p] = leaky_f(a2[p]);
        }
    }
    {   // neg branch
        float r0[4], r1[4], r2[4];
        float a0[4] = {}, a1[4] = {}, a2[4] = {};
        #pragma unroll
        for (int p = 0; p < 4; ++p) {
            r0[p] = fmaxf(-d0[p], 0.f); r1[p] = fmaxf(-d1[p], 0.f); r2[p] = fmaxf(-d2[p], 0.f);
        }
        #pragma unroll
        for (int m = 0; m < 16; ++m) {
            float w0 = Wn1[m], w1 = Wn1[16 + m], w2 = Wn1[32 + m];
            float u0 = Wn2[3 * m], u1 = Wn2[3 * m + 1], u2 = Wn2[3 * m + 2];
            #pragma unroll
            for (int p = 0; p < 4; ++p) {
                float t = fmaf(r0[p], w0, fmaf(r1[p], w1, r2[p] * w2));
                t = gelu_poly(t);
                a0[p] = fmaf(t, u0, a0[p]);
                a1[p] = fmaf(t, u1, a1[p]);
                a2[p] = fmaf(t, u2, a2[p]);
            }
        }
        #pragma unroll
        for (int p = 0; p < 4; ++p) {
            nv0[p] = leaky_f(a0[p]); nv1[p] = leaky_f(a1[p]); nv2[p] = leaky_f(a2[p]);
        }
    }
    float c00 = Wc[0], c01 = Wc[1], c02 = Wc[2];
    float c10 = Wc[3], c11 = Wc[4], c12 = Wc[5];
    float c20 = Wc[6], c21 = Wc[7], c22 = Wc[8];
    float b0 = bc[0], b1 = bc[1], b2 = bc[2];

    long base = (long)bi * NN;
    #pragma unroll
    for (int p = 0; p < 4; ++p) {
        int j = tid + p * 256;
        float q0 = pp0[p] * nv0[p], q1 = pp1[p] * nv1[p], q2 = pp2[p] * nv2[p];
        float c0 = leaky_f(fmaf(q0, c00, fmaf(q1, c10, fmaf(q2, c20, b0))));
        float c1 = leaky_f(fmaf(q0, c01, fmaf(q1, c11, fmaf(q2, c21, b1))));
        float c2 = leaky_f(fmaf(q0, c02, fmaf(q1, c12, fmaf(q2, c22, b2))));
        md[base + j]               = c0 * d0[p];
        md[MDPLANE + base + j]     = c1 * d1[p];
        md[2 * MDPLANE + base + j] = c2 * d2[p];
    }
}

__global__ __launch_bounds__(256) void fused_mid(const float* __restrict__ xyz,
                                                 const float* __restrict__ Wp1,
                                                 const float* __restrict__ Wp2,
                                                 const float* __restrict__ Wn1,
                                                 const float* __restrict__ Wn2,
                                                 const float* __restrict__ Wc,
                                                 const float* __restrict__ bc,
                                                 float* __restrict__ md,
                                                 const __hip_bfloat16* __restrict__ xb,
                                                 const __hip_bfloat16* __restrict__ Wt,
                                                 __hip_bfloat16* __restrict__ qb,
                                                 __hip_bfloat16* __restrict__ kb,
                                                 __hip_bfloat16* __restrict__ vtb) {
    int bx = blockIdx.x;
    if (bx < 4096)
        dmlp_body(bx, xyz, Wp1, Wp2, Wn1, Wn2, Wc, bc, md);
    else
        qkv_body(bx - 4096, xb, Wt, qb, kb, vtb);
}

// ---------------- K4: fused MFMA attention (md reg-prefetch, bf16 y out) ----------------
__global__ __launch_bounds__(256) void attn_kernel(
    const __hip_bfloat16* __restrict__ q,
    const __hip_bfloat16* __restrict__ kk,
    const __hip_bfloat16* __restrict__ vt,
    const float* __restrict__ md,
    const float* __restrict__ Wsp,
    __hip_bfloat16* __restrict__ yb)
{
    int it = blockIdx.x, h = blockIdx.y, b = blockIdx.z;
    int tid = threadIdx.x;
    int w = tid >> 6, lane = tid & 63;
    int g = lane >> 4, c = lane & 15;

    __shared__ __align__(16) __hip_bfloat16 k_lds[2][64][64];
    __shared__ __align__(16) __hip_bfloat16 v_lds[2][64][64];   // V^T tile: [d][j]
    __shared__ __align__(16) __hip_bfloat16 p_lds[4][16][64];

    const __hip_bfloat16* qp = q + ((long)(b * HEADS + h) * NN + it * 64) * DH;
    const __hip_bfloat16* kp = kk + (long)(b * HEADS + h) * NN * DH;
    const __hip_bfloat16* vp = vt + (long)(b * HEADS + h) * DH * NN;

    bf16x8 qa[2];
    #pragma unroll
    for (int t2 = 0; t2 < 2; ++t2)
        qa[t2] = *reinterpret_cast<const bf16x8*>(qp + (w * 16 + c) * DH + t2 * 32 + g * 8);

    int r0 = tid >> 3;
    int d00 = (tid & 7) * 8;
    int4 kreg[2], vreg[2];

    f32x4 o[4];
    #pragma unroll
    for (int df = 0; df < 4; ++df) { o[df][0] = 0.f; o[df][1] = 0.f; o[df][2] = 0.f; o[df][3] = 0.f; }
    float m_[4] = {-1e30f, -1e30f, -1e30f, -1e30f};
    float l_[4] = {0.f, 0.f, 0.f, 0.f};
    float wdx[4] = {0.f, 0.f, 0.f, 0.f}, wdy[4] = {0.f, 0.f, 0.f, 0.f}, wdz[4] = {0.f, 0.f, 0.f, 0.f};

    #pragma unroll
    for (int c2 = 0; c2 < 2; ++c2) {
        int r = r0 + c2 * 32;
        kreg[c2] = *reinterpret_cast<const int4*>(kp + (0 * 64 + r) * DH + d00);
        vreg[c2] = *reinterpret_cast<const int4*>(vp + (long)r * NN + 0 * 64 + d00);
    }
    #pragma unroll
    for (int c2 = 0; c2 < 2; ++c2) {
        int r = r0 + c2 * 32;
        int sd = d00 ^ ((r & 7) << 3);
        *reinterpret_cast<int4*>(&k_lds[0][r][sd]) = kreg[c2];
        *reinterpret_cast<int4*>(&v_lds[0][r][sd]) = vreg[c2];
    }

    const float* md0 = md;
    const float* md1 = md + MDPLANE;
    const float* md2 = md + 2 * MDPLANE;
    long mdrow = (long)(b * NN + it * 64 + w * 16 + g * 4) * NN + c;

    // md double-buffered register prefetch (rule #20: all-static indexing via macro rotation)
    float mdA[4][4][3], mdB[4][4][3];
    #pragma unroll
    for (int r = 0; r < 4; ++r) {
        long off = mdrow + (long)r * NN;            // tile 0
        #pragma unroll
        for (int jf = 0; jf < 4; ++jf) {
            mdA[r][jf][0] = md0[off + jf * 16];
            mdA[r][jf][1] = md1[off + jf * 16];
            mdA[r][jf][2] = md2[off + jf * 16];
        }
    }
    __syncthreads();

#define ATTN_STEP(T, MDC, MDN)                                                            \
    do {                                                                                  \
        int t = (T);                                                                      \
        int buf = t & 1;                                                                  \
        if (t + 1 < NT) {                                                                 \
            _Pragma("unroll")                                                             \
            for (int c2 = 0; c2 < 2; ++c2) {                                              \
                int r = r0 + c2 * 32;                                                     \
                kreg[c2] = *reinterpret_cast<const int4*>(kp + ((t + 1) * 64 + r) * DH + d00); \
                vreg[c2] = *reinterpret_cast<const int4*>(vp + (long)r * NN + (t + 1) * 64 + d00); \
            }                                                                             \
            _Pragma("unroll")                                                             \
            for (int r = 0; r < 4; ++r) {                                                 \
                long off = mdrow + (long)r * NN + (t + 1) * 64;                           \
                _Pragma("unroll")                                                         \
                for (int jf = 0; jf < 4; ++jf) {                                          \
                    MDN[r][jf][0] = md0[off + jf * 16];                                   \
                    MDN[r][jf][1] = md1[off + jf * 16];                                   \
                    MDN[r][jf][2] = md2[off + jf * 16];                                   \
                }                                                                         \
            }                                                                             \
        }                                                                                 \
        f32x4 s[4];                                                                       \
        _Pragma("unroll")                                                                 \
        for (int jf = 0; jf < 4; ++jf) {                                                  \
            f32x4 acc = {0.f, 0.f, 0.f, 0.f};                                             \
            int jl = jf * 16 + c;                                                         \
            int sw = (jl & 7) << 3;                                                       \
            _Pragma("unroll")                                                             \
            for (int t2 = 0; t2 < 2; ++t2) {                                              \
                bf16x8 bk = *reinterpret_cast<const bf16x8*>(&k_lds[buf][jl][(t2 * 32 + g * 8) ^ sw]); \
                acc = __builtin_amdgcn_mfma_f32_16x16x32_bf16(qa[t2], bk, acc, 0, 0, 0);  \
            }                                                                             \
            s[jf] = acc;                                                                  \
        }                                                                                 \
        float pe[4][4];                                                                   \
        _Pragma("unroll")                                                                 \
        for (int r = 0; r < 4; ++r) {                                                     \
            float tm = fmaxf(fmaxf(s[0][r], s[1][r]), fmaxf(s[2][r], s[3][r]));           \
            tm = fmaxf(tm, __shfl_xor(tm, 1));                                            \
            tm = fmaxf(tm, __shfl_xor(tm, 2));                                            \
            tm = fmaxf(tm, __shfl_xor(tm, 4));                                            \
            tm = fmaxf(tm, __shfl_xor(tm, 8));                                            \
            float nm = fmaxf(m_[r], tm);                                                  \
            float corr = __expf(m_[r] - nm);                                              \
            m_[r] = nm;                                                                   \
            l_[r] *= corr;                                                                \
            wdx[r] *= corr; wdy[r] *= corr; wdz[r] *= corr;                               \
            o[0][r] *= corr; o[1][r] *= corr; o[2][r] *= corr; o[3][r] *= corr;           \
            float ps = 0.f;                                                               \
            _Pragma("unroll")                                                             \
            for (int jf = 0; jf < 4; ++jf) {                                              \
                float p = __expf(s[jf][r] - nm);                                          \
                pe[r][jf] = p;                                                            \
                ps += p;                                                                  \
            }                                                                             \
            l_[r] += ps;                                                                  \
        }                                                                                 \
        _Pragma("unroll")                                                                 \
        for (int r = 0; r < 4; ++r) {                                                     \
            int row = g * 4 + r;                                                          \
            int sw = (row & 7) << 3;                                                      \
            _Pragma("unroll")                                                             \
            for (int jf = 0; jf < 4; ++jf)                                                \
                p_lds[w][row][(jf * 16 + c) ^ sw] = __float2bfloat16(pe[r][jf]);          \
        }                                                                                 \
        asm volatile("s_waitcnt lgkmcnt(0)" ::: "memory");                                \
        _Pragma("unroll")                                                                 \
        for (int r = 0; r < 4; ++r) {                                                     \
            _Pragma("unroll")                                                             \
            for (int jf = 0; jf < 4; ++jf) {                                              \
                wdx[r] = fmaf(pe[r][jf], MDC[r][jf][0], wdx[r]);                          \
                wdy[r] = fmaf(pe[r][jf], MDC[r][jf][1], wdy[r]);                          \
                wdz[r] = fmaf(pe[r][jf], MDC[r][jf][2], wdz[r]);                          \
            }                                                                             \
        }                                                                                 \
        _Pragma("unroll")                                                                 \
        for (int t2 = 0; t2 < 2; ++t2) {                                                  \
            int swp = (c & 7) << 3;                                                       \
            bf16x8 pa = *reinterpret_cast<const bf16x8*>(&p_lds[w][c][(t2 * 32 + g * 8) ^ swp]); \
            _Pragma("unroll")                                                             \
            for (int df = 0; df < 4; ++df) {                                              \
                int dl = df * 16 + c;                                                     \
                int swv = (dl & 7) << 3;                                                  \
                bf16x8 bv = *reinterpret_cast<const bf16x8*>(&v_lds[buf][dl][(t2 * 32 + g * 8) ^ swv]); \
                o[df] = __builtin_amdgcn_mfma_f32_16x16x32_bf16(pa, bv, o[df], 0, 0, 0);  \
            }                                                                             \
        }                                                                                 \
        if (t + 1 < NT) {                                                                 \
            _Pragma("unroll")                                                             \
            for (int c2 = 0; c2 < 2; ++c2) {                                              \
                int r = r0 + c2 * 32;                                                     \
                int sd = d00 ^ ((r & 7) << 3);                                            \
                *reinterpret_cast<int4*>(&k_lds[buf ^ 1][r][sd]) = kreg[c2];              \
                *reinterpret_cast<int4*>(&v_lds[buf ^ 1][r][sd]) = vreg[c2];              \
            }                                                                             \
        }                                                                                 \
        __syncthreads();                                                                  \
    } while (0)

    for (int tt = 0; tt < NT; tt += 2) {
        ATTN_STEP(tt, mdA, mdB);
        ATTN_STEP(tt + 1, mdB, mdA);
    }
#undef ATTN_STEP

    #pragma unroll
    for (int r = 0; r < 4; ++r) {
        float lv = l_[r];
        lv += __shfl_xor(lv, 1); lv += __shfl_xor(lv, 2);
        lv += __shfl_xor(lv, 4); lv += __shfl_xor(lv, 8);
        float w0 = wdx[r], w1 = wdy[r], w2 = wdz[r];
        w0 += __shfl_xor(w0, 1); w0 += __shfl_xor(w0, 2); w0 += __shfl_xor(w0, 4); w0 += __shfl_xor(w0, 8);
        w1 += __shfl_xor(w1, 1); w1 += __shfl_xor(w1, 2); w1 += __shfl_xor(w1, 4); w1 += __shfl_xor(w1, 8);
        w2 += __shfl_xor(w2, 1); w2 += __shfl_xor(w2, 2); w2 += __shfl_xor(w2, 4); w2 += __shfl_xor(w2, 8);
        float inv = 1.0f / lv;
        w0 *= inv; w1 *= inv; w2 *= inv;
        int row = g * 4 + r;
        long ig = (long)b * NN + it * 64 + w * 16 + row;
        __hip_bfloat16* yp = yb + ig * INNERD + h * DH;
        #pragma unroll
        for (int df = 0; df < 4; ++df) {
            int d = df * 16 + c;
            float disp = w0 * Wsp[d] + w1 * Wsp[64 + d] + w2 * Wsp[128 + d];
            yp[d] = __float2bfloat16(o[df][r] * inv + disp);
        }
    }
}

// ---------------- K5: MFMA output projection + GELU + residual ----------------
// grid (64 m-tiles, 4 n-tiles), block 256 = 4 waves; wave = 16 rows x 64 cols; K=512.
__global__ __launch_bounds__(256) void out_gemm(const __hip_bfloat16* __restrict__ yb,
                                                const __hip_bfloat16* __restrict__ Wot,
                                                const float* __restrict__ bout,
                                                const float* __restrict__ feat,
                                                float* __restrict__ out) {
    int mt = blockIdx.x, nt = blockIdx.y;
    int tid = threadIdx.x, w = tid >> 6, lane = tid & 63;
    int g = lane >> 4, c = lane & 15;

    const __hip_bfloat16* ap = yb + ((long)mt * 64 + w * 16 + c) * INNERD + g * 8;
    bf16x8 a[16];
    #pragma unroll
    for (int ks = 0; ks < 16; ++ks) a[ks] = *reinterpret_cast<const bf16x8*>(ap + ks * 32);

    f32x4 acc[4];
    #pragma unroll
    for (int jf = 0; jf < 4; ++jf) { acc[jf][0] = 0.f; acc[jf][1] = 0.f; acc[jf][2] = 0.f; acc[jf][3] = 0.f; }

    const __hip_bfloat16* bp = Wot + (nt * 64 + c) * INNERD + g * 8;
    #pragma unroll
    for (int jf = 0; jf < 4; ++jf) {
        const __hip_bfloat16* bpj = bp + jf * 16 * INNERD;
        #pragma unroll
        for (int ks = 0; ks < 16; ++ks) {
            bf16x8 bfrag = *reinterpret_cast<const bf16x8*>(bpj + ks * 32);
            acc[jf] = __builtin_amdgcn_mfma_f32_16x16x32_bf16(a[ks], bfrag, acc[jf], 0, 0, 0);
        }
    }

    #pragma unroll
    for (int jf = 0; jf < 4; ++jf) {
        int d = nt * 64 + jf * 16 + c;
        float bo = bout[d];
        #pragma unroll
        for (int r = 0; r < 4; ++r) {
            long m = (long)mt * 64 + w * 16 + g * 4 + r;
            float val = gelu_poly(acc[jf][r] + bo);
            out[m * DIMM + d] = val + feat[m * DIMM + d];
        }
    }
}

extern "C" void kernel_launch(void* const* d_in, const int* in_sizes, int n_in,
                              void* d_out, int out_size, void* d_ws, size_t ws_size,
                              hipStream_t stream) {
    const float* xyzs  = (const float*)d_in[0];
    const float* feat  = (const float*)d_in[1];
    const float* gamma = (const float*)d_in[2];
    const float* beta  = (const float*)d_in[3];
    const float* Wqkv  = (const float*)d_in[4];
    const float* Wp1   = (const float*)d_in[5];
    const float* Wp2   = (const float*)d_in[6];
    const float* Wn1   = (const float*)d_in[7];
    const float* Wn2   = (const float*)d_in[8];
    const float* Wc    = (const float*)d_in[9];
    const float* bc    = (const float*)d_in[10];
    const float* Wsp   = (const float*)d_in[11];
    const float* Wout  = (const float*)d_in[12];
    const float* bout  = (const float*)d_in[13];
    float* out = (float*)d_out;

    // workspace (bf16 elems): xb 1M | Wt 384K | Wot 128K | qb 2M | kb 2M | vtb 2M | yb 2M | md 12M f32
    __hip_bfloat16* xb  = (__hip_bfloat16*)d_ws;
    __hip_bfloat16* Wt  = xb + 1048576;
    __hip_bfloat16* Wot = Wt + 393216;
    __hip_bfloat16* qb  = Wot + 131072;
    __hip_bfloat16* kb  = qb + 2097152;
    __hip_bfloat16* vtb = kb + 2097152;
    __hip_bfloat16* yb  = vtb + 2097152;
    float* md = (float*)(yb + 2097152);

    ln_kernel<<<4096, 256, 0, stream>>>(feat, gamma, beta, xb);
    wtg_kernel<<<dim3(24, 4), 256, 0, stream>>>(Wqkv, Wt, 1536, 256);
    wtg_kernel<<<dim3(4, 8), 256, 0, stream>>>(Wout, Wot, 256, 512);
    fused_mid<<<5632, 256, 0, stream>>>(xyzs, Wp1, Wp2, Wn1, Wn2, Wc, bc, md,
                                        xb, Wt, qb, kb, vtb);
    attn_kernel<<<dim3(16, HEADS, BB), 256, 0, stream>>>(qb, kb, vtb, md, Wsp, yb);
    out_gemm<<<dim3(64, 4), 256, 0, stream>>>(yb, Wot, bout, feat, out);
}

// Round 7
// 134.317 us; speedup vs baseline: 1.3573x; 1.3573x over previous
//
#include <hip/hip_runtime.h>
#include <hip/hip_bf16.h>
#include <math.h>

#define BB 4
#define NN 1024
#define DIMM 256
#define HEADS 8
#define DH 64
#define INNERD 512
#define NT 16
#define MDPLANE 4194304   // B*N*N

typedef __bf16 bf16x8 __attribute__((ext_vector_type(8)));
typedef float f32x4 __attribute__((ext_vector_type(4)));

// Trans-free GELU: clamp to [-3,3] + degree-9 odd poly for erf(x/sqrt2).
__device__ __forceinline__ float gelu_poly(float x) {
    float xc = fminf(fmaxf(x, -3.0f), 3.0f);
    float u = xc * xc;
    float f = fmaf(u, fmaf(u, fmaf(u, fmaf(u, 4.4413e-5f, -1.33195e-3f),
                                   1.70980e-2f), -1.299964e-1f), 7.9734583e-1f);
    float E = xc * f;
    float hx = 0.5f * xc;
    float g = fmaf(hx, E, hx);
    return g + fmaxf(x - 3.0f, 0.0f);
}
__device__ __forceinline__ float leaky_f(float x) {
    return fmaxf(x, 0.01f * x);
}

// ---------------- K1: LayerNorm (bf16 out) ----------------
__global__ __launch_bounds__(256) void ln_kernel(const float* __restrict__ feat,
                                                 const float* __restrict__ gamma,
                                                 const float* __restrict__ beta,
                                                 __hip_bfloat16* __restrict__ xb) {
    int row = blockIdx.x;
    int t = threadIdx.x;
    float v = feat[row * DIMM + t];
    float s = v, ss = v * v;
    #pragma unroll
    for (int off = 1; off < 64; off <<= 1) {
        s += __shfl_xor(s, off);
        ss += __shfl_xor(ss, off);
    }
    __shared__ float red[2][4];
    int w = t >> 6, lane = t & 63;
    if (lane == 0) { red[0][w] = s; red[1][w] = ss; }
    __syncthreads();
    s = red[0][0] + red[0][1] + red[0][2] + red[0][3];
    ss = red[1][0] + red[1][1] + red[1][2] + red[1][3];
    float mu = s * (1.0f / DIMM);
    float var = ss * (1.0f / DIMM) - mu * mu;
    float rs = rsqrtf(var + 1e-5f);
    xb[row * DIMM + t] = __float2bfloat16((v - mu) * rs * gamma[t] + beta[t]);
}

// ---------------- K2a: generic transpose-convert W[R][C] f32 -> Wt[C][R] bf16 ----------------
__global__ __launch_bounds__(256) void wtg_kernel(const float* __restrict__ W,
                                                  __hip_bfloat16* __restrict__ Wt,
                                                  int C, int R) {
    __shared__ float tile[64][65];
    int n0 = blockIdx.x * 64, k0 = blockIdx.y * 64;
    int tid = threadIdx.x;
    int cc = tid & 63, rr = tid >> 6;
    #pragma unroll
    for (int p = 0; p < 16; ++p) {
        int k = rr + p * 4;
        tile[k][cc] = W[(k0 + k) * C + n0 + cc];
    }
    __syncthreads();
    #pragma unroll
    for (int p = 0; p < 16; ++p) {
        int n = rr + p * 4;
        Wt[(n0 + n) * R + k0 + cc] = __float2bfloat16(tile[cc][n]);
    }
}

// ---------------- fused mid: dmlp blocks (0..4095) || qkv GEMM blocks (4096..5631) ----------------
__device__ __forceinline__ void qkv_body(int bx,
                                         const __hip_bfloat16* __restrict__ xb,
                                         const __hip_bfloat16* __restrict__ Wt,
                                         __hip_bfloat16* __restrict__ qb,
                                         __hip_bfloat16* __restrict__ kb,
                                         __hip_bfloat16* __restrict__ vtb) {
    int mt = bx & 63, nt = bx >> 6;
    int tid = threadIdx.x, w = tid >> 6, lane = tid & 63;
    int g = lane >> 4, c = lane & 15;

    const __hip_bfloat16* ap = xb + (mt * 64 + w * 16 + c) * 256 + g * 8;
    bf16x8 a[8];
    #pragma unroll
    for (int ks = 0; ks < 8; ++ks) a[ks] = *reinterpret_cast<const bf16x8*>(ap + ks * 32);

    f32x4 acc[4];
    #pragma unroll
    for (int jf = 0; jf < 4; ++jf) { acc[jf][0] = 0.f; acc[jf][1] = 0.f; acc[jf][2] = 0.f; acc[jf][3] = 0.f; }

    const __hip_bfloat16* bp = Wt + (nt * 64 + c) * 256 + g * 8;
    #pragma unroll
    for (int jf = 0; jf < 4; ++jf) {
        const __hip_bfloat16* bpj = bp + jf * 16 * 256;
        #pragma unroll
        for (int ks = 0; ks < 8; ++ks) {
            bf16x8 bfrag = *reinterpret_cast<const bf16x8*>(bpj + ks * 32);
            acc[jf] = __builtin_amdgcn_mfma_f32_16x16x32_bf16(a[ks], bfrag, acc[jf], 0, 0, 0);
        }
    }

    int col0 = nt * 64;
    int part = col0 >> 9;            // 0=q,1=k,2=v
    int h = (col0 >> 6) & 7;
    #pragma unroll
    for (int jf = 0; jf < 4; ++jf) {
        int d = jf * 16 + c;
        #pragma unroll
        for (int r = 0; r < 4; ++r) {
            int m = mt * 64 + w * 16 + g * 4 + r;
            int b = m >> 10, nn = m & 1023;
            if (part == 0)
                qb[(((b * HEADS + h) * NN) + nn) * DH + d] = __float2bfloat16(acc[jf][r] * 0.125f);
            else if (part == 1)
                kb[(((b * HEADS + h) * NN) + nn) * DH + d] = __float2bfloat16(acc[jf][r]);
            else
                vtb[((long)(b * HEADS + h) * DH + d) * NN + nn] = __float2bfloat16(acc[jf][r]);
        }
    }
}

__device__ __forceinline__ void dmlp_body(int bi,
                                          const float* __restrict__ xyz,
                                          const float* __restrict__ Wp1,
                                          const float* __restrict__ Wp2,
                                          const float* __restrict__ Wn1,
                                          const float* __restrict__ Wn2,
                                          const float* __restrict__ Wc,
                                          const float* __restrict__ bc,
                                          __hip_bfloat16* __restrict__ md) {
    int tid = threadIdx.x;
    int b = bi >> 10;
    const float* xj = xyz + (long)b * NN * 3;
    float xi0 = xyz[bi * 3 + 0], xi1 = xyz[bi * 3 + 1], xi2 = xyz[bi * 3 + 2];

    float d0[4], d1[4], d2[4];
    #pragma unroll
    for (int p = 0; p < 4; ++p) {
        int j = tid + p * 256;
        d0[p] = xj[j * 3 + 0] - xi0;
        d1[p] = xj[j * 3 + 1] - xi1;
        d2[p] = xj[j * 3 + 2] - xi2;
    }

    float pp0[4], pp1[4], pp2[4], nv0[4], nv1[4], nv2[4];
    {   // pos branch
        float r0[4], r1[4], r2[4];
        float a0[4] = {}, a1[4] = {}, a2[4] = {};
        #pragma unroll
        for (int p = 0; p < 4; ++p) {
            r0[p] = fmaxf(d0[p], 0.f); r1[p] = fmaxf(d1[p], 0.f); r2[p] = fmaxf(d2[p], 0.f);
        }
        #pragma unroll
        for (int m = 0; m < 16; ++m) {
            float w0 = Wp1[m], w1 = Wp1[16 + m], w2 = Wp1[32 + m];
            float u0 = Wp2[3 * m], u1 = Wp2[3 * m + 1], u2 = Wp2[3 * m + 2];
            #pragma unroll
            for (int p = 0; p < 4; ++p) {
                float t = fmaf(r0[p], w0, fmaf(r1[p], w1, r2[p] * w2));
                t = gelu_poly(t);
                a0[p] = fmaf(t, u0, a0[p]);
                a1[p] = fmaf(t, u1, a1[p]);
                a2[p] = fmaf(t, u2, a2[p]);
            }
        }
        #pragma unroll
        for (int p = 0; p < 4; ++p) {
            pp0[p] = leaky_f(a0[p]); pp1[p] = leaky_f(a1[p]); pp2[p] = leaky_f(a2[p]);
        }
    }
    {   // neg branch
        float r0[4], r1[4], r2[4];
        float a0[4] = {}, a1[4] = {}, a2[4] = {};
        #pragma unroll
        for (int p = 0; p < 4; ++p) {
            r0[p] = fmaxf(-d0[p], 0.f); r1[p] = fmaxf(-d1[p], 0.f); r2[p] = fmaxf(-d2[p], 0.f);
        }
        #pragma unroll
        for (int m = 0; m < 16; ++m) {
            float w0 = Wn1[m], w1 = Wn1[16 + m], w2 = Wn1[32 + m];
            float u0 = Wn2[3 * m], u1 = Wn2[3 * m + 1], u2 = Wn2[3 * m + 2];
            #pragma unroll
            for (int p = 0; p < 4; ++p) {
                float t = fmaf(r0[p], w0, fmaf(r1[p], w1, r2[p] * w2));
                t = gelu_poly(t);
                a0[p] = fmaf(t, u0, a0[p]);
                a1[p] = fmaf(t, u1, a1[p]);
                a2[p] = fmaf(t, u2, a2[p]);
            }
        }
        #pragma unroll
        for (int p = 0; p < 4; ++p) {
            nv0[p] = leaky_f(a0[p]); nv1[p] = leaky_f(a1[p]); nv2[p] = leaky_f(a2[p]);
        }
    }
    float c00 = Wc[0], c01 = Wc[1], c02 = Wc[2];
    float c10 = Wc[3], c11 = Wc[4], c12 = Wc[5];
    float c20 = Wc[6], c21 = Wc[7], c22 = Wc[8];
    float b0 = bc[0], b1 = bc[1], b2 = bc[2];

    long base = (long)bi * NN;
    #pragma unroll
    for (int p = 0; p < 4; ++p) {
        int j = tid + p * 256;
        float q0 = pp0[p] * nv0[p], q1 = pp1[p] * nv1[p], q2 = pp2[p] * nv2[p];
        float c0 = leaky_f(fmaf(q0, c00, fmaf(q1, c10, fmaf(q2, c20, b0))));
        float c1 = leaky_f(fmaf(q0, c01, fmaf(q1, c11, fmaf(q2, c21, b1))));
        float c2 = leaky_f(fmaf(q0, c02, fmaf(q1, c12, fmaf(q2, c22, b2))));
        md[base + j]               = __float2bfloat16(c0 * d0[p]);
        md[MDPLANE + base + j]     = __float2bfloat16(c1 * d1[p]);
        md[2 * MDPLANE + base + j] = __float2bfloat16(c2 * d2[p]);
    }
}

__global__ __launch_bounds__(256) void fused_mid(const float* __restrict__ xyz,
                                                 const float* __restrict__ Wp1,
                                                 const float* __restrict__ Wp2,
                                                 const float* __restrict__ Wn1,
                                                 const float* __restrict__ Wn2,
                                                 const float* __restrict__ Wc,
                                                 const float* __restrict__ bc,
                                                 __hip_bfloat16* __restrict__ md,
                                                 const __hip_bfloat16* __restrict__ xb,
                                                 const __hip_bfloat16* __restrict__ Wt,
                                                 __hip_bfloat16* __restrict__ qb,
                                                 __hip_bfloat16* __restrict__ kb,
                                                 __hip_bfloat16* __restrict__ vtb) {
    int bx = blockIdx.x;
    if (bx < 4096)
        dmlp_body(bx, xyz, Wp1, Wp2, Wn1, Wn2, Wc, bc, md);
    else
        qkv_body(bx - 4096, xb, Wt, qb, kb, vtb);
}

// ---------------- K4: fused MFMA attention (R5 structure; bf16 md, hoisted loads) ----------------
__global__ __launch_bounds__(256) void attn_kernel(
    const __hip_bfloat16* __restrict__ q,
    const __hip_bfloat16* __restrict__ kk,
    const __hip_bfloat16* __restrict__ vt,
    const __hip_bfloat16* __restrict__ md,
    const float* __restrict__ Wsp,
    __hip_bfloat16* __restrict__ yb)
{
    int it = blockIdx.x, h = blockIdx.y, b = blockIdx.z;
    int tid = threadIdx.x;
    int w = tid >> 6, lane = tid & 63;
    int g = lane >> 4, c = lane & 15;

    __shared__ __align__(16) __hip_bfloat16 k_lds[2][64][64];
    __shared__ __align__(16) __hip_bfloat16 v_lds[2][64][64];   // V^T tile: [d][j]
    __shared__ __align__(16) __hip_bfloat16 p_lds[4][16][64];

    const __hip_bfloat16* qp = q + ((long)(b * HEADS + h) * NN + it * 64) * DH;
    const __hip_bfloat16* kp = kk + (long)(b * HEADS + h) * NN * DH;
    const __hip_bfloat16* vp = vt + (long)(b * HEADS + h) * DH * NN;

    bf16x8 qa[2];
    #pragma unroll
    for (int t2 = 0; t2 < 2; ++t2)
        qa[t2] = *reinterpret_cast<const bf16x8*>(qp + (w * 16 + c) * DH + t2 * 32 + g * 8);

    int r0 = tid >> 3;
    int d00 = (tid & 7) * 8;
    int4 kreg[2], vreg[2];

    f32x4 o[4];
    #pragma unroll
    for (int df = 0; df < 4; ++df) { o[df][0] = 0.f; o[df][1] = 0.f; o[df][2] = 0.f; o[df][3] = 0.f; }
    float m_[4] = {-1e30f, -1e30f, -1e30f, -1e30f};
    float l_[4] = {0.f, 0.f, 0.f, 0.f};
    float wdx[4] = {0.f, 0.f, 0.f, 0.f}, wdy[4] = {0.f, 0.f, 0.f, 0.f}, wdz[4] = {0.f, 0.f, 0.f, 0.f};

    #pragma unroll
    for (int c2 = 0; c2 < 2; ++c2) {
        int r = r0 + c2 * 32;
        kreg[c2] = *reinterpret_cast<const int4*>(kp + (0 * 64 + r) * DH + d00);
        vreg[c2] = *reinterpret_cast<const int4*>(vp + (long)r * NN + 0 * 64 + d00);
    }
    #pragma unroll
    for (int c2 = 0; c2 < 2; ++c2) {
        int r = r0 + c2 * 32;
        int sd = d00 ^ ((r & 7) << 3);
        *reinterpret_cast<int4*>(&k_lds[0][r][sd]) = kreg[c2];
        *reinterpret_cast<int4*>(&v_lds[0][r][sd]) = vreg[c2];
    }
    __syncthreads();

    const __hip_bfloat16* md0 = md;
    const __hip_bfloat16* md1 = md + MDPLANE;
    const __hip_bfloat16* md2 = md + 2 * MDPLANE;
    long mdrow = (long)(b * NN + it * 64 + w * 16 + g * 4) * NN + c;

    for (int t = 0; t < NT; ++t) {
        int buf = t & 1;
        if (t + 1 < NT) {
            #pragma unroll
            for (int c2 = 0; c2 < 2; ++c2) {
                int r = r0 + c2 * 32;
                kreg[c2] = *reinterpret_cast<const int4*>(kp + ((t + 1) * 64 + r) * DH + d00);
                vreg[c2] = *reinterpret_cast<const int4*>(vp + (long)r * NN + (t + 1) * 64 + d00);
            }
        }

        // hoisted current-tile md loads (issue early; waited on at wdelta use)
        float mdc[4][4][3];
        #pragma unroll
        for (int r = 0; r < 4; ++r) {
            long off = mdrow + (long)r * NN + t * 64;
            #pragma unroll
            for (int jf = 0; jf < 4; ++jf) {
                mdc[r][jf][0] = __bfloat162float(md0[off + jf * 16]);
                mdc[r][jf][1] = __bfloat162float(md1[off + jf * 16]);
                mdc[r][jf][2] = __bfloat162float(md2[off + jf * 16]);
            }
        }

        f32x4 s[4];
        #pragma unroll
        for (int jf = 0; jf < 4; ++jf) {
            f32x4 acc = {0.f, 0.f, 0.f, 0.f};
            int jl = jf * 16 + c;
            int sw = (jl & 7) << 3;
            #pragma unroll
            for (int t2 = 0; t2 < 2; ++t2) {
                bf16x8 bk = *reinterpret_cast<const bf16x8*>(&k_lds[buf][jl][(t2 * 32 + g * 8) ^ sw]);
                acc = __builtin_amdgcn_mfma_f32_16x16x32_bf16(qa[t2], bk, acc, 0, 0, 0);
            }
            s[jf] = acc;
        }

        float pe[4][4];
        #pragma unroll
        for (int r = 0; r < 4; ++r) {
            float tm = fmaxf(fmaxf(s[0][r], s[1][r]), fmaxf(s[2][r], s[3][r]));
            tm = fmaxf(tm, __shfl_xor(tm, 1));
            tm = fmaxf(tm, __shfl_xor(tm, 2));
            tm = fmaxf(tm, __shfl_xor(tm, 4));
            tm = fmaxf(tm, __shfl_xor(tm, 8));
            float nm = fmaxf(m_[r], tm);
            float corr = __expf(m_[r] - nm);
            m_[r] = nm;
            l_[r] *= corr;
            wdx[r] *= corr; wdy[r] *= corr; wdz[r] *= corr;
            o[0][r] *= corr; o[1][r] *= corr; o[2][r] *= corr; o[3][r] *= corr;
            float ps = 0.f;
            #pragma unroll
            for (int jf = 0; jf < 4; ++jf) {
                float p = __expf(s[jf][r] - nm);
                pe[r][jf] = p;
                ps += p;
            }
            l_[r] += ps;
        }

        #pragma unroll
        for (int r = 0; r < 4; ++r) {
            int row = g * 4 + r;
            int sw = (row & 7) << 3;
            #pragma unroll
            for (int jf = 0; jf < 4; ++jf)
                p_lds[w][row][(jf * 16 + c) ^ sw] = __float2bfloat16(pe[r][jf]);
        }
        asm volatile("s_waitcnt lgkmcnt(0)" ::: "memory");

        #pragma unroll
        for (int r = 0; r < 4; ++r) {
            #pragma unroll
            for (int jf = 0; jf < 4; ++jf) {
                wdx[r] = fmaf(pe[r][jf], mdc[r][jf][0], wdx[r]);
                wdy[r] = fmaf(pe[r][jf], mdc[r][jf][1], wdy[r]);
                wdz[r] = fmaf(pe[r][jf], mdc[r][jf][2], wdz[r]);
            }
        }

        #pragma unroll
        for (int t2 = 0; t2 < 2; ++t2) {
            int swp = (c & 7) << 3;
            bf16x8 pa = *reinterpret_cast<const bf16x8*>(&p_lds[w][c][(t2 * 32 + g * 8) ^ swp]);
            #pragma unroll
            for (int df = 0; df < 4; ++df) {
                int dl = df * 16 + c;
                int swv = (dl & 7) << 3;
                bf16x8 bv = *reinterpret_cast<const bf16x8*>(&v_lds[buf][dl][(t2 * 32 + g * 8) ^ swv]);
                o[df] = __builtin_amdgcn_mfma_f32_16x16x32_bf16(pa, bv, o[df], 0, 0, 0);
            }
        }

        if (t + 1 < NT) {
            #pragma unroll
            for (int c2 = 0; c2 < 2; ++c2) {
                int r = r0 + c2 * 32;
                int sd = d00 ^ ((r & 7) << 3);
                *reinterpret_cast<int4*>(&k_lds[buf ^ 1][r][sd]) = kreg[c2];
                *reinterpret_cast<int4*>(&v_lds[buf ^ 1][r][sd]) = vreg[c2];
            }
        }
        __syncthreads();
    }

    #pragma unroll
    for (int r = 0; r < 4; ++r) {
        float lv = l_[r];
        lv += __shfl_xor(lv, 1); lv += __shfl_xor(lv, 2);
        lv += __shfl_xor(lv, 4); lv += __shfl_xor(lv, 8);
        float w0 = wdx[r], w1 = wdy[r], w2 = wdz[r];
        w0 += __shfl_xor(w0, 1); w0 += __shfl_xor(w0, 2); w0 += __shfl_xor(w0, 4); w0 += __shfl_xor(w0, 8);
        w1 += __shfl_xor(w1, 1); w1 += __shfl_xor(w1, 2); w1 += __shfl_xor(w1, 4); w1 += __shfl_xor(w1, 8);
        w2 += __shfl_xor(w2, 1); w2 += __shfl_xor(w2, 2); w2 += __shfl_xor(w2, 4); w2 += __shfl_xor(w2, 8);
        float inv = 1.0f / lv;
        w0 *= inv; w1 *= inv; w2 *= inv;
        int row = g * 4 + r;
        long ig = (long)b * NN + it * 64 + w * 16 + row;
        __hip_bfloat16* yp = yb + ig * INNERD + h * DH;
        #pragma unroll
        for (int df = 0; df < 4; ++df) {
            int d = df * 16 + c;
            float disp = w0 * Wsp[d] + w1 * Wsp[64 + d] + w2 * Wsp[128 + d];
            yp[d] = __float2bfloat16(o[df][r] * inv + disp);
        }
    }
}

// ---------------- K5: MFMA output projection + GELU + residual ----------------
__global__ __launch_bounds__(256) void out_gemm(const __hip_bfloat16* __restrict__ yb,
                                                const __hip_bfloat16* __restrict__ Wot,
                                                const float* __restrict__ bout,
                                                const float* __restrict__ feat,
                                                float* __restrict__ out) {
    int mt = blockIdx.x, nt = blockIdx.y;
    int tid = threadIdx.x, w = tid >> 6, lane = tid & 63;
    int g = lane >> 4, c = lane & 15;

    const __hip_bfloat16* ap = yb + ((long)mt * 64 + w * 16 + c) * INNERD + g * 8;
    bf16x8 a[16];
    #pragma unroll
    for (int ks = 0; ks < 16; ++ks) a[ks] = *reinterpret_cast<const bf16x8*>(ap + ks * 32);

    f32x4 acc[4];
    #pragma unroll
    for (int jf = 0; jf < 4; ++jf) { acc[jf][0] = 0.f; acc[jf][1] = 0.f; acc[jf][2] = 0.f; acc[jf][3] = 0.f; }

    const __hip_bfloat16* bp = Wot + (nt * 64 + c) * INNERD + g * 8;
    #pragma unroll
    for (int jf = 0; jf < 4; ++jf) {
        const __hip_bfloat16* bpj = bp + jf * 16 * INNERD;
        #pragma unroll
        for (int ks = 0; ks < 16; ++ks) {
            bf16x8 bfrag = *reinterpret_cast<const bf16x8*>(bpj + ks * 32);
            acc[jf] = __builtin_amdgcn_mfma_f32_16x16x32_bf16(a[ks], bfrag, acc[jf], 0, 0, 0);
        }
    }

    #pragma unroll
    for (int jf = 0; jf < 4; ++jf) {
        int d = nt * 64 + jf * 16 + c;
        float bo = bout[d];
        #pragma unroll
        for (int r = 0; r < 4; ++r) {
            long m = (long)mt * 64 + w * 16 + g * 4 + r;
            float val = gelu_poly(acc[jf][r] + bo);
            out[m * DIMM + d] = val + feat[m * DIMM + d];
        }
    }
}

extern "C" void kernel_launch(void* const* d_in, const int* in_sizes, int n_in,
                              void* d_out, int out_size, void* d_ws, size_t ws_size,
                              hipStream_t stream) {
    const float* xyzs  = (const float*)d_in[0];
    const float* feat  = (const float*)d_in[1];
    const float* gamma = (const float*)d_in[2];
    const float* beta  = (const float*)d_in[3];
    const float* Wqkv  = (const float*)d_in[4];
    const float* Wp1   = (const float*)d_in[5];
    const float* Wp2   = (const float*)d_in[6];
    const float* Wn1   = (const float*)d_in[7];
    const float* Wn2   = (const float*)d_in[8];
    const float* Wc    = (const float*)d_in[9];
    const float* bc    = (const float*)d_in[10];
    const float* Wsp   = (const float*)d_in[11];
    const float* Wout  = (const float*)d_in[12];
    const float* bout  = (const float*)d_in[13];
    float* out = (float*)d_out;

    // workspace (bf16 elems): xb 1M | Wt 384K | Wot 128K | qb 2M | kb 2M | vtb 2M | yb 2M | md 12M bf16
    __hip_bfloat16* xb  = (__hip_bfloat16*)d_ws;
    __hip_bfloat16* Wt  = xb + 1048576;
    __hip_bfloat16* Wot = Wt + 393216;
    __hip_bfloat16* qb  = Wot + 131072;
    __hip_bfloat16* kb  = qb + 2097152;
    __hip_bfloat16* vtb = kb + 2097152;
    __hip_bfloat16* yb  = vtb + 2097152;
    __hip_bfloat16* md  = yb + 2097152;

    ln_kernel<<<4096, 256, 0, stream>>>(feat, gamma, beta, xb);
    wtg_kernel<<<dim3(24, 4), 256, 0, stream>>>(Wqkv, Wt, 1536, 256);
    wtg_kernel<<<dim3(4, 8), 256, 0, stream>>>(Wout, Wot, 256, 512);
    fused_mid<<<5632, 256, 0, stream>>>(xyzs, Wp1, Wp2, Wn1, Wn2, Wc, bc, md,
                                        xb, Wt, qb, kb, vtb);
    attn_kernel<<<dim3(16, HEADS, BB), 256, 0, stream>>>(qb, kb, vtb, md, Wsp, yb);
    out_gemm<<<dim3(64, 4), 256, 0, stream>>>(yb, Wot, bout, feat, out);
}